// Round 2
// baseline (1915.066 us; speedup 1.0000x reference)
//
#include <hip/hip_runtime.h>
#include <hip/hip_bf16.h>
#include <math.h>
#include <stdio.h>

#define B_ 32
#define S_ 128
#define L_ 1024
#define D_ 1024

typedef unsigned short u16;

__device__ __forceinline__ float bf2f(u16 u) {
    return __uint_as_float(((unsigned)u) << 16);
}
__device__ __forceinline__ u16 f2bf(float f) {
    unsigned u = __float_as_uint(f);
    u += 0x7FFF + ((u >> 16) & 1);
    return (u16)(u >> 16);
}
__device__ __forceinline__ float gelu_tanh(float x) {
    float x3 = x * x * x;
    float t = tanhf(0.7978845608028654f * (x + 0.044715f * x3));
    return 0.5f * x * (1.0f + t);
}
__device__ __forceinline__ float sigmoidf(float x) {
    return 1.0f / (1.0f + expf(-x));
}

// ---------------- K0: S4D SSM kernel, writes Kt[j][d] (j-major, 64x1024) ----
__global__ __launch_bounds__(256) void k_ssmk(
        const float* __restrict__ log_dt, const float* __restrict__ Alr,
        const float* __restrict__ Aim, const float* __restrict__ Cr,
        const float* __restrict__ Ci, float* __restrict__ Kt) {
    int tid = blockIdx.x * 256 + threadIdx.x;   // 65536 total
    int d = tid & (D_ - 1);
    int j = tid >> 10;                           // 0..63
    float dt = expf(log_dt[d]);
    float acc = 0.f;
    #pragma unroll
    for (int n = 0; n < 4; ++n) {
        float ar = -expf(Alr[d * 4 + n]);
        float ai = Aim[d * 4 + n];
        float wr = ar * dt, wi = ai * dt;        // dtA
        float ew = expf(wr);
        float sw, cw; sincosf(wi, &sw, &cw);
        float ur = ew * cw - 1.0f, ui = ew * sw;
        float inv = 1.0f / (ar * ar + ai * ai);
        float bdr = (ur * ar + ui * ai) * inv;
        float bdi = (ui * ar - ur * ai) * inv;
        float cr = Cr[d * 4 + n], ci = Ci[d * 4 + n];
        float cbr = cr * bdr - ci * bdi;
        float cbi = cr * bdi + ci * bdr;
        float ej = expf(wr * (float)j);
        float sj, cj; sincosf(wi * (float)j, &sj, &cj);
        acc += 2.0f * ej * (cbr * cj - cbi * sj);
    }
    Kt[j * D_ + d] = acc;
}

// ---------------- K1: encoder h[b,l,e] = sum_d u[b,d,l] W[d,e] + be[e] ------
// tile 64(l) x 64(e), K=128; writes hb as bf16
__global__ __launch_bounds__(256) void k_encoder(
        const float* __restrict__ x, const float* __restrict__ We,
        const float* __restrict__ be, u16* __restrict__ hb) {
    __shared__ float Ut[64][68];   // [k][l]
    __shared__ float Wt[64][68];   // [k][e]
    int b = blockIdx.z;
    int l0 = blockIdx.y * 64;
    int e0 = blockIdx.x * 64;
    int t = threadIdx.x;
    int tx = t & 15, ty = t >> 4;
    float acc[4][4] = {};
    for (int kt = 0; kt < 2; ++kt) {
        int k0 = kt * 64;
        __syncthreads();
        #pragma unroll
        for (int p = 0; p < 4; ++p) {
            int fid = p * 256 + t;
            int r = fid >> 4, c4 = fid & 15;
            float4 v = *(const float4*)&x[(size_t)b * 131072 + (size_t)(k0 + r) * 1024 + l0 + c4 * 4];
            *(float4*)&Ut[r][c4 * 4] = v;
            float4 w = *(const float4*)&We[(size_t)(k0 + r) * 1024 + e0 + c4 * 4];
            *(float4*)&Wt[r][c4 * 4] = w;
        }
        __syncthreads();
        #pragma unroll
        for (int k = 0; k < 64; ++k) {
            float4 a = *(const float4*)&Ut[k][tx * 4];
            float4 bb = *(const float4*)&Wt[k][ty * 4];
            float av[4] = {a.x, a.y, a.z, a.w};
            float bv[4] = {bb.x, bb.y, bb.z, bb.w};
            #pragma unroll
            for (int i = 0; i < 4; ++i)
                #pragma unroll
                for (int q = 0; q < 4; ++q)
                    acc[i][q] = fmaf(av[i], bv[q], acc[i][q]);
        }
    }
    float bev[4];
    #pragma unroll
    for (int q = 0; q < 4; ++q) bev[q] = be[e0 + ty * 4 + q];
    #pragma unroll
    for (int i = 0; i < 4; ++i) {
        int l = l0 + tx * 4 + i;
        ushort4 o;
        o.x = f2bf(acc[i][0] + bev[0]);
        o.y = f2bf(acc[i][1] + bev[1]);
        o.z = f2bf(acc[i][2] + bev[2]);
        o.w = f2bf(acc[i][3] + bev[3]);
        *(ushort4*)&hb[((size_t)b * 1024 + l) * 1024 + e0 + ty * 4] = o;
    }
}

// ---------------- K2: causal 64-tap conv + D*skip + GELU -------------------
__global__ __launch_bounds__(256) void k_conv(
        const u16* __restrict__ hb, const float* __restrict__ Kt,
        const float* __restrict__ Dv, u16* __restrict__ yg) {
    __shared__ float hs[128][64];
    int b = blockIdx.z;
    int l0 = blockIdx.y * 64;
    int d0 = blockIdx.x * 64;
    int t = threadIdx.x;
    int dl = t & 63, lg = t >> 6;
    #pragma unroll
    for (int p = 0; p < 8; ++p) {
        int fid = p * 256 + t;
        int r = fid >> 4, c4 = fid & 15;
        int l = l0 - 64 + r;
        float4 v = make_float4(0.f, 0.f, 0.f, 0.f);
        if (l >= 0) {
            ushort4 u = *(const ushort4*)&hb[((size_t)b * 1024 + l) * 1024 + d0 + c4 * 4];
            v = make_float4(bf2f(u.x), bf2f(u.y), bf2f(u.z), bf2f(u.w));
        }
        *(float4*)&hs[r][c4 * 4] = v;
    }
    float kr[64];
    #pragma unroll
    for (int j = 0; j < 64; ++j) kr[j] = Kt[j * 1024 + d0 + dl];
    float Dd = Dv[d0 + dl];
    __syncthreads();
    float acc[16] = {};
    int rbase = lg * 16 + 1;   // LDS row for s=0
    #pragma unroll
    for (int s = 0; s < 15; ++s) {
        float hv = hs[rbase + s][dl];
        #pragma unroll
        for (int i = 0; i <= 14; ++i)
            if (i <= s) acc[i] = fmaf(kr[i + 63 - s], hv, acc[i]);
    }
    #pragma unroll
    for (int s = 15; s < 64; ++s) {
        float hv = hs[rbase + s][dl];
        #pragma unroll
        for (int i = 0; i < 16; ++i)
            acc[i] = fmaf(kr[i + 63 - s], hv, acc[i]);
    }
    #pragma unroll
    for (int s = 64; s < 79; ++s) {
        float hv = hs[rbase + s][dl];
        #pragma unroll
        for (int i = 1; i < 16; ++i)
            if (i >= s - 63) acc[i] = fmaf(kr[i + 63 - s], hv, acc[i]);
    }
    #pragma unroll
    for (int i = 0; i < 16; ++i) {
        int l = l0 + lg * 16 + i;
        float z = hs[64 + lg * 16 + i][dl];
        float y = acc[i] + Dd * z;
        yg[((size_t)b * 1024 + l) * 1024 + d0 + dl] = f2bf(gelu_tanh(y));
    }
}

// ---------------- K3: GLU GEMM + residual in-place into hb ------------------
// tile 128(m) x 64(n paired with n+1024), BK=16; r = hb + g1*sigmoid(g2)
__global__ __launch_bounds__(256) void k_glu(
        const u16* __restrict__ yg, const float* __restrict__ Wg,
        const float* __restrict__ bg, u16* __restrict__ hb) {
    __shared__ float At[16][132];   // [k][m 128]
    __shared__ float Bs[16][132];   // [k][n-pair 128]
    int m0 = blockIdx.y * 128;
    int n0 = blockIdx.x * 64;
    int t = threadIdx.x;
    int tx = t & 15, ty = t >> 4;
    float acc[8][8] = {};
    for (int kt = 0; kt < 64; ++kt) {
        int k0 = kt * 16;
        __syncthreads();
        #pragma unroll
        for (int p = 0; p < 2; ++p) {
            int fid = p * 256 + t;
            int mm = fid >> 2, k4 = fid & 3;
            ushort4 u = *(const ushort4*)&yg[(size_t)(m0 + mm) * 1024 + k0 + k4 * 4];
            At[k4 * 4 + 0][mm] = bf2f(u.x); At[k4 * 4 + 1][mm] = bf2f(u.y);
            At[k4 * 4 + 2][mm] = bf2f(u.z); At[k4 * 4 + 3][mm] = bf2f(u.w);
        }
        #pragma unroll
        for (int p = 0; p < 2; ++p) {
            int fid = p * 256 + t;
            int kk = fid >> 5, c4 = fid & 31;
            int col = (c4 < 16) ? (n0 + c4 * 4) : (1024 + n0 + (c4 - 16) * 4);
            float4 v = *(const float4*)&Wg[(size_t)(k0 + kk) * 2048 + col];
            *(float4*)&Bs[kk][c4 * 4] = v;
        }
        __syncthreads();
        #pragma unroll
        for (int k = 0; k < 16; ++k) {
            float av[8], bv[8];
            *(float4*)&av[0] = *(const float4*)&At[k][tx * 8];
            *(float4*)&av[4] = *(const float4*)&At[k][tx * 8 + 4];
            *(float4*)&bv[0] = *(const float4*)&Bs[k][ty * 4];
            *(float4*)&bv[4] = *(const float4*)&Bs[k][ty * 4 + 64];
            #pragma unroll
            for (int i = 0; i < 8; ++i)
                #pragma unroll
                for (int q = 0; q < 8; ++q)
                    acc[i][q] = fmaf(av[i], bv[q], acc[i][q]);
        }
    }
    float b1[4], b2[4];
    #pragma unroll
    for (int q = 0; q < 4; ++q) {
        b1[q] = bg[n0 + ty * 4 + q];
        b2[q] = bg[1024 + n0 + ty * 4 + q];
    }
    #pragma unroll
    for (int i = 0; i < 8; ++i) {
        size_t m = (size_t)(m0 + tx * 8 + i);
        ushort4 hv = *(const ushort4*)&hb[m * 1024 + n0 + ty * 4];
        float hf[4] = {bf2f(hv.x), bf2f(hv.y), bf2f(hv.z), bf2f(hv.w)};
        ushort4 o;
        float r0, r1, r2, r3;
        r0 = hf[0] + (acc[i][0] + b1[0]) * sigmoidf(acc[i][4] + b2[0]);
        r1 = hf[1] + (acc[i][1] + b1[1]) * sigmoidf(acc[i][5] + b2[1]);
        r2 = hf[2] + (acc[i][2] + b1[2]) * sigmoidf(acc[i][6] + b2[2]);
        r3 = hf[3] + (acc[i][3] + b1[3]) * sigmoidf(acc[i][7] + b2[3]);
        o.x = f2bf(r0); o.y = f2bf(r1); o.z = f2bf(r2); o.w = f2bf(r3);
        *(ushort4*)&hb[m * 1024 + n0 + ty * 4] = o;
    }
}

// ---------------- K4: LayerNorm in-place on hb ------------------------------
__global__ __launch_bounds__(256) void k_ln(
        u16* __restrict__ hb, const float* __restrict__ gamma,
        const float* __restrict__ beta) {
    int row = blockIdx.x;
    int t = threadIdx.x;
    size_t base = (size_t)row * 1024;
    ushort4 u = *(const ushort4*)&hb[base + t * 4];
    float v0 = bf2f(u.x), v1 = bf2f(u.y), v2 = bf2f(u.z), v3 = bf2f(u.w);
    float s = v0 + v1 + v2 + v3;
    float s2 = v0 * v0 + v1 * v1 + v2 * v2 + v3 * v3;
    #pragma unroll
    for (int off = 32; off > 0; off >>= 1) {
        s += __shfl_down(s, off);
        s2 += __shfl_down(s2, off);
    }
    __shared__ float rs[4], rs2[4];
    int wid = t >> 6, lane = t & 63;
    if (lane == 0) { rs[wid] = s; rs2[wid] = s2; }
    __syncthreads();
    float ts = rs[0] + rs[1] + rs[2] + rs[3];
    float ts2 = rs2[0] + rs2[1] + rs2[2] + rs2[3];
    float mean = ts * (1.0f / 1024.0f);
    float var = ts2 * (1.0f / 1024.0f) - mean * mean;
    float rstd = rsqrtf(var + 1e-5f);
    float4 gm = *(const float4*)&gamma[t * 4];
    float4 bt = *(const float4*)&beta[t * 4];
    ushort4 o;
    o.x = f2bf((v0 - mean) * rstd * gm.x + bt.x);
    o.y = f2bf((v1 - mean) * rstd * gm.y + bt.y);
    o.z = f2bf((v2 - mean) * rstd * gm.z + bt.z);
    o.w = f2bf((v3 - mean) * rstd * gm.w + bt.w);
    *(ushort4*)&hb[base + t * 4] = o;
}

// ---------------- K5: decoder GEMM + transpose to (b, s, l) ----------------
__global__ __launch_bounds__(256) void k_dec(
        const u16* __restrict__ hb, const float* __restrict__ Wd,
        const float* __restrict__ bd, float* __restrict__ out) {
    __shared__ float At[16][68];    // [k][m 64]
    __shared__ float Bs[16][132];   // [k][s 128]
    __shared__ float Ts[128][68];   // [s][m]
    int m0 = blockIdx.x * 64;
    int b = m0 >> 10, l0 = m0 & 1023;
    int t = threadIdx.x;
    int tx = t & 15, ty = t >> 4;
    float acc[4][8] = {};
    for (int kt = 0; kt < 64; ++kt) {
        int k0 = kt * 16;
        __syncthreads();
        {
            int mm = t >> 2, k4 = t & 3;
            ushort4 u = *(const ushort4*)&hb[(size_t)(m0 + mm) * 1024 + k0 + k4 * 4];
            At[k4 * 4 + 0][mm] = bf2f(u.x); At[k4 * 4 + 1][mm] = bf2f(u.y);
            At[k4 * 4 + 2][mm] = bf2f(u.z); At[k4 * 4 + 3][mm] = bf2f(u.w);
        }
        #pragma unroll
        for (int p = 0; p < 2; ++p) {
            int fid = p * 256 + t;
            int kk = fid >> 5, c4 = fid & 31;
            float4 v = *(const float4*)&Wd[(size_t)(k0 + kk) * 128 + c4 * 4];
            *(float4*)&Bs[kk][c4 * 4] = v;
        }
        __syncthreads();
        #pragma unroll
        for (int k = 0; k < 16; ++k) {
            float av[4], bv[8];
            *(float4*)&av[0] = *(const float4*)&At[k][tx * 4];
            *(float4*)&bv[0] = *(const float4*)&Bs[k][ty * 8];
            *(float4*)&bv[4] = *(const float4*)&Bs[k][ty * 8 + 4];
            #pragma unroll
            for (int i = 0; i < 4; ++i)
                #pragma unroll
                for (int q = 0; q < 8; ++q)
                    acc[i][q] = fmaf(av[i], bv[q], acc[i][q]);
        }
    }
    __syncthreads();
    #pragma unroll
    for (int q = 0; q < 8; ++q) {
        int s = ty * 8 + q;
        float bias = bd[s];
        #pragma unroll
        for (int i = 0; i < 4; ++i)
            Ts[s][tx * 4 + i] = acc[i][q] + bias;
    }
    __syncthreads();
    #pragma unroll
    for (int p = 0; p < 8; ++p) {
        int fid = p * 256 + t;
        int s = fid >> 4, c4 = fid & 15;
        float4 v = *(const float4*)&Ts[s][c4 * 4];
        *(float4*)&out[(size_t)b * 131072 + (size_t)s * 1024 + l0 + c4 * 4] = v;
    }
}

extern "C" void kernel_launch(void* const* d_in, const int* in_sizes, int n_in,
                              void* d_out, int out_size, void* d_ws, size_t ws_size,
                              hipStream_t stream) {
    (void)in_sizes; (void)n_in; (void)out_size;
    fprintf(stderr, "[kernel_launch] ws_size=%zu bytes (need %zu)\n",
            ws_size, (size_t)(33554432ull * 2 * 2 + 65536ull * 4));
    const float* x   = (const float*)d_in[0];
    const float* We  = (const float*)d_in[1];
    const float* be  = (const float*)d_in[2];
    const float* ldt = (const float*)d_in[3];
    const float* Alr = (const float*)d_in[4];
    const float* Aim = (const float*)d_in[5];
    const float* Cr  = (const float*)d_in[6];
    const float* Ci  = (const float*)d_in[7];
    const float* Dv  = (const float*)d_in[8];
    const float* Wg  = (const float*)d_in[9];
    const float* bg  = (const float*)d_in[10];
    const float* gam = (const float*)d_in[11];
    const float* bet = (const float*)d_in[12];
    const float* Wd  = (const float*)d_in[13];
    const float* bd  = (const float*)d_in[14];
    float* out = (float*)d_out;

    u16* hb = (u16*)d_ws;                       // 32*1024*1024 bf16 = 67 MB
    u16* yg = hb + 33554432ull;                 // 67 MB
    float* Kt = (float*)(yg + 33554432ull);     // 64*1024 f32 = 256 KB

    k_ssmk<<<256, 256, 0, stream>>>(ldt, Alr, Aim, Cr, Ci, Kt);
    k_encoder<<<dim3(16, 16, 32), 256, 0, stream>>>(x, We, be, hb);
    k_conv<<<dim3(16, 16, 32), 256, 0, stream>>>(hb, Kt, Dv, yg);
    k_glu<<<dim3(16, 256), 256, 0, stream>>>(yg, Wg, bg, hb);
    k_ln<<<32768, 256, 0, stream>>>(hb, gam, bet);
    k_dec<<<512, 256, 0, stream>>>(hb, Wd, bd, out);
}

// Round 3
// 508.790 us; speedup vs baseline: 3.7640x; 3.7640x over previous
//
#include <hip/hip_runtime.h>
#include <hip/hip_bf16.h>
#include <math.h>

#define B_ 32
#define S_ 128
#define L_ 1024
#define D_ 1024

typedef unsigned short u16;
typedef __attribute__((ext_vector_type(8))) __bf16 bf16x8;
typedef __attribute__((ext_vector_type(4))) float f32x4;

__device__ __forceinline__ float bf2f(u16 u) {
    return __uint_as_float(((unsigned)u) << 16);
}
__device__ __forceinline__ u16 f2bf(float f) {
    unsigned u = __float_as_uint(f);
    u += 0x7FFF + ((u >> 16) & 1);
    return (u16)(u >> 16);
}
__device__ __forceinline__ float gelu_tanh(float x) {
    float x3 = x * x * x;
    float t = tanhf(0.7978845608028654f * (x + 0.044715f * x3));
    return 0.5f * x * (1.0f + t);
}
__device__ __forceinline__ float sigmoidf(float x) {
    return 1.0f / (1.0f + expf(-x));
}
__device__ __forceinline__ void gld16(const void* g, void* l) {
    __builtin_amdgcn_global_load_lds((const __attribute__((address_space(1))) void*)g,
                                     (__attribute__((address_space(3))) void*)l, 16, 0, 0);
}

// ---------------- K0: S4D SSM kernel, writes Kt[j][d] (j-major, 64x1024) ----
__global__ __launch_bounds__(256) void k_ssmk(
        const float* __restrict__ log_dt, const float* __restrict__ Alr,
        const float* __restrict__ Aim, const float* __restrict__ Cr,
        const float* __restrict__ Ci, float* __restrict__ Kt) {
    int tid = blockIdx.x * 256 + threadIdx.x;
    int d = tid & (D_ - 1);
    int j = tid >> 10;
    float dt = expf(log_dt[d]);
    float acc = 0.f;
    #pragma unroll
    for (int n = 0; n < 4; ++n) {
        float ar = -expf(Alr[d * 4 + n]);
        float ai = Aim[d * 4 + n];
        float wr = ar * dt, wi = ai * dt;
        float ew = expf(wr);
        float sw, cw; sincosf(wi, &sw, &cw);
        float ur = ew * cw - 1.0f, ui = ew * sw;
        float inv = 1.0f / (ar * ar + ai * ai);
        float bdr = (ur * ar + ui * ai) * inv;
        float bdi = (ui * ar - ur * ai) * inv;
        float cr = Cr[d * 4 + n], ci = Ci[d * 4 + n];
        float cbr = cr * bdr - ci * bdi;
        float cbi = cr * bdi + ci * bdr;
        float ej = expf(wr * (float)j);
        float sj, cj; sincosf(wi * (float)j, &sj, &cj);
        acc += 2.0f * ej * (cbr * cj - cbi * sj);
    }
    Kt[j * D_ + d] = acc;
}

// ---------------- transpose+cast: src f32 [R][C] -> dst bf16 [C][R] --------
__global__ __launch_bounds__(256) void k_tcast(
        const float* __restrict__ src, u16* __restrict__ dst, int R, int C) {
    __shared__ float tile[64][65];
    int c0 = blockIdx.x * 64;
    int r0 = blockIdx.y * 64;
    int t = threadIdx.x;
    #pragma unroll
    for (int p = 0; p < 4; ++p) {
        int fid = p * 256 + t;
        int rr = fid >> 4, cc = (fid & 15) * 4;
        float4 v = *(const float4*)&src[(size_t)(r0 + rr) * C + c0 + cc];
        tile[rr][cc + 0] = v.x; tile[rr][cc + 1] = v.y;
        tile[rr][cc + 2] = v.z; tile[rr][cc + 3] = v.w;
    }
    __syncthreads();
    #pragma unroll
    for (int p = 0; p < 4; ++p) {
        int fid = p * 256 + t;
        int rr = fid >> 4, cc = (fid & 15) * 4;   // rr: dst-row (c-dim), cc: dst-col (r-dim)
        ushort4 o;
        o.x = f2bf(tile[cc + 0][rr]);
        o.y = f2bf(tile[cc + 1][rr]);
        o.z = f2bf(tile[cc + 2][rr]);
        o.w = f2bf(tile[cc + 3][rr]);
        *(ushort4*)&dst[(size_t)(c0 + rr) * R + r0 + cc] = o;
    }
}

// ---------------- K1: encoder h[b,l,e] = sum_d u[b,d,l] W[d,e] + be[e] ------
__global__ __launch_bounds__(256) void k_encoder(
        const float* __restrict__ x, const float* __restrict__ We,
        const float* __restrict__ be, u16* __restrict__ hb) {
    __shared__ float Ut[64][68];
    __shared__ float Wt[64][68];
    int b = blockIdx.z;
    int l0 = blockIdx.y * 64;
    int e0 = blockIdx.x * 64;
    int t = threadIdx.x;
    int tx = t & 15, ty = t >> 4;
    float acc[4][4] = {};
    for (int kt = 0; kt < 2; ++kt) {
        int k0 = kt * 64;
        __syncthreads();
        #pragma unroll
        for (int p = 0; p < 4; ++p) {
            int fid = p * 256 + t;
            int r = fid >> 4, c4 = fid & 15;
            float4 v = *(const float4*)&x[(size_t)b * 131072 + (size_t)(k0 + r) * 1024 + l0 + c4 * 4];
            *(float4*)&Ut[r][c4 * 4] = v;
            float4 w = *(const float4*)&We[(size_t)(k0 + r) * 1024 + e0 + c4 * 4];
            *(float4*)&Wt[r][c4 * 4] = w;
        }
        __syncthreads();
        #pragma unroll
        for (int k = 0; k < 64; ++k) {
            float4 a = *(const float4*)&Ut[k][tx * 4];
            float4 bb = *(const float4*)&Wt[k][ty * 4];
            float av[4] = {a.x, a.y, a.z, a.w};
            float bv[4] = {bb.x, bb.y, bb.z, bb.w};
            #pragma unroll
            for (int i = 0; i < 4; ++i)
                #pragma unroll
                for (int q = 0; q < 4; ++q)
                    acc[i][q] = fmaf(av[i], bv[q], acc[i][q]);
        }
    }
    float bev[4];
    #pragma unroll
    for (int q = 0; q < 4; ++q) bev[q] = be[e0 + ty * 4 + q];
    #pragma unroll
    for (int i = 0; i < 4; ++i) {
        int l = l0 + tx * 4 + i;
        ushort4 o;
        o.x = f2bf(acc[i][0] + bev[0]);
        o.y = f2bf(acc[i][1] + bev[1]);
        o.z = f2bf(acc[i][2] + bev[2]);
        o.w = f2bf(acc[i][3] + bev[3]);
        *(ushort4*)&hb[((size_t)b * 1024 + l) * 1024 + e0 + ty * 4] = o;
    }
}

// ---------------- K2: causal 64-tap conv + D*skip + GELU -------------------
__global__ __launch_bounds__(256) void k_conv(
        const u16* __restrict__ hb, const float* __restrict__ Kt,
        const float* __restrict__ Dv, u16* __restrict__ yg) {
    __shared__ float hs[128][64];
    int b = blockIdx.z;
    int l0 = blockIdx.y * 64;
    int d0 = blockIdx.x * 64;
    int t = threadIdx.x;
    int dl = t & 63, lg = t >> 6;
    #pragma unroll
    for (int p = 0; p < 8; ++p) {
        int fid = p * 256 + t;
        int r = fid >> 4, c4 = fid & 15;
        int l = l0 - 64 + r;
        float4 v = make_float4(0.f, 0.f, 0.f, 0.f);
        if (l >= 0) {
            ushort4 u = *(const ushort4*)&hb[((size_t)b * 1024 + l) * 1024 + d0 + c4 * 4];
            v = make_float4(bf2f(u.x), bf2f(u.y), bf2f(u.z), bf2f(u.w));
        }
        *(float4*)&hs[r][c4 * 4] = v;
    }
    float kr[64];
    #pragma unroll
    for (int j = 0; j < 64; ++j) kr[j] = Kt[j * 1024 + d0 + dl];
    float Dd = Dv[d0 + dl];
    __syncthreads();
    float acc[16] = {};
    int rbase = lg * 16 + 1;
    #pragma unroll
    for (int s = 0; s < 15; ++s) {
        float hv = hs[rbase + s][dl];
        #pragma unroll
        for (int i = 0; i <= 14; ++i)
            if (i <= s) acc[i] = fmaf(kr[i + 63 - s], hv, acc[i]);
    }
    #pragma unroll
    for (int s = 15; s < 64; ++s) {
        float hv = hs[rbase + s][dl];
        #pragma unroll
        for (int i = 0; i < 16; ++i)
            acc[i] = fmaf(kr[i + 63 - s], hv, acc[i]);
    }
    #pragma unroll
    for (int s = 64; s < 79; ++s) {
        float hv = hs[rbase + s][dl];
        #pragma unroll
        for (int i = 1; i < 16; ++i)
            if (i >= s - 63) acc[i] = fmaf(kr[i + 63 - s], hv, acc[i]);
    }
    #pragma unroll
    for (int i = 0; i < 16; ++i) {
        int l = l0 + lg * 16 + i;
        float z = hs[64 + lg * 16 + i][dl];
        float y = acc[i] + Dd * z;
        yg[((size_t)b * 1024 + l) * 1024 + d0 + dl] = f2bf(gelu_tanh(y));
    }
}

// ---------------- K3: GLU GEMM (bf16 MFMA) + activation + residual ---------
// 128(m) x 64 pairs; A=yg [m][k] bf16, B=WgT [n][k] bf16. BK=64, 16 k-steps.
// LDS B row rr -> global col: half=(rr>>4)&1, pairIdx=((rr>>5)<<4)|(rr&15)
__global__ __launch_bounds__(256) void k_glu_mfma(
        const u16* __restrict__ yg, const u16* __restrict__ WgT,
        const float* __restrict__ bg, u16* __restrict__ hb) {
    __shared__ u16 As[128 * 64];
    __shared__ u16 Bs[128 * 64];
    int t = threadIdx.x;
    int lane = t & 63, wid = t >> 6;
    int wr = wid & 1, wc = wid >> 1;

    int orig = blockIdx.x;
    int wgid = (orig & 7) * 512 + (orig >> 3);   // XCD-chunked swizzle (4096 % 8 == 0)
    int m0 = (wgid >> 4) * 128;
    int p0 = (wgid & 15) * 64;

    // staging geometry
    int ch_r = lane >> 3;
    int ks = (lane & 7) * 8;
    int rA[4], nB[4];
    #pragma unroll
    for (int c = 0; c < 4; ++c) {
        int r = (wid * 4 + c) * 8 + ch_r;        // 0..127
        rA[c] = m0 + r;
        int pairIdx = ((r >> 5) << 4) | (r & 15);
        int half = (r >> 4) & 1;
        nB[c] = half * 1024 + p0 + pairIdx;
    }
    // fragment read offsets (u16 elems)
    int aoff[4], boff[4];
    #pragma unroll
    for (int i = 0; i < 4; ++i)
        aoff[i] = (wr * 64 + i * 16 + (lane & 15)) * 64 + (lane >> 4) * 8;
    #pragma unroll
    for (int q = 0; q < 4; ++q)
        boff[q] = (wc * 64 + q * 16 + (lane & 15)) * 64 + (lane >> 4) * 8;

    f32x4 acc[4][4] = {};
    for (int kt = 0; kt < 16; ++kt) {
        int k0 = kt * 64;
        __syncthreads();
        #pragma unroll
        for (int c = 0; c < 4; ++c) {
            int ch = wid * 4 + c;
            gld16(&yg[(size_t)rA[c] * 1024 + k0 + ks], &As[ch * 512]);
            gld16(&WgT[(size_t)nB[c] * 1024 + k0 + ks], &Bs[ch * 512]);
        }
        __syncthreads();
        #pragma unroll
        for (int kh = 0; kh < 2; ++kh) {
            bf16x8 af[4], bfr[4];
            #pragma unroll
            for (int i = 0; i < 4; ++i) af[i] = *(const bf16x8*)&As[aoff[i] + kh * 32];
            #pragma unroll
            for (int q = 0; q < 4; ++q) bfr[q] = *(const bf16x8*)&Bs[boff[q] + kh * 32];
            #pragma unroll
            for (int i = 0; i < 4; ++i)
                #pragma unroll
                for (int q = 0; q < 4; ++q)
                    acc[i][q] = __builtin_amdgcn_mfma_f32_16x16x32_bf16(af[i], bfr[q], acc[i][q], 0, 0, 0);
        }
    }
    // epilogue: pairs (frag 2qq = g1, frag 2qq+1 = g2), residual in-place
    #pragma unroll
    for (int i = 0; i < 4; ++i) {
        #pragma unroll
        for (int qq = 0; qq < 2; ++qq) {
            int pair = (wc * 2 + qq) * 16 + (lane & 15);
            int col = p0 + pair;
            float b1v = bg[col];
            float b2v = bg[1024 + col];
            #pragma unroll
            for (int r = 0; r < 4; ++r) {
                int m = m0 + wr * 64 + i * 16 + (lane >> 4) * 4 + r;
                float g1 = acc[i][qq * 2][r] + b1v;
                float g2 = acc[i][qq * 2 + 1][r] + b2v;
                size_t idx = (size_t)m * 1024 + col;
                float hf = bf2f(hb[idx]);
                hb[idx] = f2bf(hf + g1 * sigmoidf(g2));
            }
        }
    }
}

// ---------------- K4: LayerNorm in-place on hb ------------------------------
__global__ __launch_bounds__(256) void k_ln(
        u16* __restrict__ hb, const float* __restrict__ gamma,
        const float* __restrict__ beta) {
    int row = blockIdx.x;
    int t = threadIdx.x;
    size_t base = (size_t)row * 1024;
    ushort4 u = *(const ushort4*)&hb[base + t * 4];
    float v0 = bf2f(u.x), v1 = bf2f(u.y), v2 = bf2f(u.z), v3 = bf2f(u.w);
    float s = v0 + v1 + v2 + v3;
    float s2 = v0 * v0 + v1 * v1 + v2 * v2 + v3 * v3;
    #pragma unroll
    for (int off = 32; off > 0; off >>= 1) {
        s += __shfl_down(s, off);
        s2 += __shfl_down(s2, off);
    }
    __shared__ float rs[4], rs2[4];
    int wid = t >> 6, lane = t & 63;
    if (lane == 0) { rs[wid] = s; rs2[wid] = s2; }
    __syncthreads();
    float ts = rs[0] + rs[1] + rs[2] + rs[3];
    float ts2 = rs2[0] + rs2[1] + rs2[2] + rs2[3];
    float mean = ts * (1.0f / 1024.0f);
    float var = ts2 * (1.0f / 1024.0f) - mean * mean;
    float rstd = rsqrtf(var + 1e-5f);
    float4 gm = *(const float4*)&gamma[t * 4];
    float4 bt = *(const float4*)&beta[t * 4];
    ushort4 o;
    o.x = f2bf((v0 - mean) * rstd * gm.x + bt.x);
    o.y = f2bf((v1 - mean) * rstd * gm.y + bt.y);
    o.z = f2bf((v2 - mean) * rstd * gm.z + bt.z);
    o.w = f2bf((v3 - mean) * rstd * gm.w + bt.w);
    *(ushort4*)&hb[base + t * 4] = o;
}

// ---------------- K5: decoder GEMM (bf16 MFMA) + transpose store -----------
// M=32768, N=128, K=1024; tile 128x128, 256 blocks.
__global__ __launch_bounds__(256) void k_dec_mfma(
        const u16* __restrict__ hb, const u16* __restrict__ WdT,
        const float* __restrict__ bd, float* __restrict__ out) {
    __shared__ __align__(16) char smem[33792];
    u16* As = (u16*)smem;              // 16KB [128][64]
    u16* Bs = (u16*)(smem + 16384);    // 16KB [128][64]
    float* Ts = (float*)smem;          // 64*132 f32 = 33792B (reused)
    int t = threadIdx.x;
    int lane = t & 63, wid = t >> 6;
    int wr = wid & 1, wc = wid >> 1;
    int m0 = blockIdx.x * 128;
    int bb = m0 >> 10, l0 = m0 & 1023;

    int ch_r = lane >> 3;
    int ks = (lane & 7) * 8;
    int aoff[4], boff[4];
    #pragma unroll
    for (int i = 0; i < 4; ++i)
        aoff[i] = (wr * 64 + i * 16 + (lane & 15)) * 64 + (lane >> 4) * 8;
    #pragma unroll
    for (int q = 0; q < 4; ++q)
        boff[q] = (wc * 64 + q * 16 + (lane & 15)) * 64 + (lane >> 4) * 8;

    f32x4 acc[4][4] = {};
    for (int kt = 0; kt < 16; ++kt) {
        int k0 = kt * 64;
        __syncthreads();
        #pragma unroll
        for (int c = 0; c < 4; ++c) {
            int ch = wid * 4 + c;
            int r = ch * 8 + ch_r;
            gld16(&hb[(size_t)(m0 + r) * 1024 + k0 + ks], &As[ch * 512]);
            gld16(&WdT[(size_t)r * 1024 + k0 + ks], &Bs[ch * 512]);
        }
        __syncthreads();
        #pragma unroll
        for (int kh = 0; kh < 2; ++kh) {
            bf16x8 af[4], bfr[4];
            #pragma unroll
            for (int i = 0; i < 4; ++i) af[i] = *(const bf16x8*)&As[aoff[i] + kh * 32];
            #pragma unroll
            for (int q = 0; q < 4; ++q) bfr[q] = *(const bf16x8*)&Bs[boff[q] + kh * 32];
            #pragma unroll
            for (int i = 0; i < 4; ++i)
                #pragma unroll
                for (int q = 0; q < 4; ++q)
                    acc[i][q] = __builtin_amdgcn_mfma_f32_16x16x32_bf16(af[i], bfr[q], acc[i][q], 0, 0, 0);
        }
    }
    __syncthreads();
    #pragma unroll
    for (int ro = 0; ro < 2; ++ro) {
        if (wc == ro) {
            #pragma unroll
            for (int i = 0; i < 4; ++i)
                #pragma unroll
                for (int q = 0; q < 4; ++q) {
                    int sl = q * 16 + (lane & 15);
                    float bias = bd[ro * 64 + sl];
                    #pragma unroll
                    for (int r = 0; r < 4; ++r) {
                        int ml = wr * 64 + i * 16 + (lane >> 4) * 4 + r;
                        Ts[sl * 132 + ml] = acc[i][q][r] + bias;
                    }
                }
        }
        __syncthreads();
        #pragma unroll
        for (int p = 0; p < 8; ++p) {
            int fid = p * 256 + t;
            int sl = fid >> 5, c = (fid & 31) * 4;
            float4 v = *(const float4*)&Ts[sl * 132 + c];
            *(float4*)&out[(size_t)bb * 131072 + (size_t)(ro * 64 + sl) * 1024 + l0 + c] = v;
        }
        __syncthreads();
    }
}

extern "C" void kernel_launch(void* const* d_in, const int* in_sizes, int n_in,
                              void* d_out, int out_size, void* d_ws, size_t ws_size,
                              hipStream_t stream) {
    (void)in_sizes; (void)n_in; (void)out_size; (void)ws_size;
    const float* x   = (const float*)d_in[0];
    const float* We  = (const float*)d_in[1];
    const float* be  = (const float*)d_in[2];
    const float* ldt = (const float*)d_in[3];
    const float* Alr = (const float*)d_in[4];
    const float* Aim = (const float*)d_in[5];
    const float* Cr  = (const float*)d_in[6];
    const float* Ci  = (const float*)d_in[7];
    const float* Dv  = (const float*)d_in[8];
    const float* Wg  = (const float*)d_in[9];
    const float* bg  = (const float*)d_in[10];
    const float* gam = (const float*)d_in[11];
    const float* bet = (const float*)d_in[12];
    const float* Wd  = (const float*)d_in[13];
    const float* bd  = (const float*)d_in[14];
    float* out = (float*)d_out;

    u16* hb = (u16*)d_ws;                       // 33554432 bf16 = 67 MB
    u16* yg = hb + 33554432ull;                 // 67 MB
    float* Kt = (float*)(yg + 33554432ull);     // 256 KB
    u16* WgT = (u16*)(Kt + 65536);              // 2048x1024 bf16 = 4 MB
    u16* WdT = WgT + 2097152ull;                // 128x1024 bf16 = 256 KB

    k_tcast<<<dim3(32, 16), 256, 0, stream>>>(Wg, WgT, 1024, 2048);
    k_tcast<<<dim3(2, 16), 256, 0, stream>>>(Wd, WdT, 1024, 128);
    k_ssmk<<<256, 256, 0, stream>>>(ldt, Alr, Aim, Cr, Ci, Kt);
    k_encoder<<<dim3(16, 16, 32), 256, 0, stream>>>(x, We, be, hb);
    k_conv<<<dim3(16, 16, 32), 256, 0, stream>>>(hb, Kt, Dv, yg);
    k_glu_mfma<<<4096, 256, 0, stream>>>(yg, WgT, bg, hb);
    k_ln<<<32768, 256, 0, stream>>>(hb, gam, bet);
    k_dec_mfma<<<256, 256, 0, stream>>>(hb, WdT, bd, out);
}

// Round 4
// 365.419 us; speedup vs baseline: 5.2407x; 1.3923x over previous
//
#include <hip/hip_runtime.h>
#include <hip/hip_bf16.h>
#include <math.h>

#define B_ 32
#define S_ 128
#define L_ 1024
#define D_ 1024

typedef unsigned short u16;
typedef __attribute__((ext_vector_type(8))) __bf16 bf16x8;
typedef __attribute__((ext_vector_type(4))) float f32x4;

__device__ __forceinline__ float bf2f(u16 u) {
    return __uint_as_float(((unsigned)u) << 16);
}
__device__ __forceinline__ u16 f2bf(float f) {
    unsigned u = __float_as_uint(f);
    u += 0x7FFF + ((u >> 16) & 1);
    return (u16)(u >> 16);
}
__device__ __forceinline__ float gelu_tanh(float x) {
    float x3 = x * x * x;
    float t = tanhf(0.7978845608028654f * (x + 0.044715f * x3));
    return 0.5f * x * (1.0f + t);
}
__device__ __forceinline__ float sigmoidf(float x) {
    return 1.0f / (1.0f + expf(-x));
}
__device__ __forceinline__ void gld16(const void* g, void* l) {
    __builtin_amdgcn_global_load_lds((const __attribute__((address_space(1))) void*)g,
                                     (__attribute__((address_space(3))) void*)l, 16, 0, 0);
}

// ---------------- K0: S4D SSM kernel, writes Kt[j][d] (j-major, 64x1024) ----
__global__ __launch_bounds__(256) void k_ssmk(
        const float* __restrict__ log_dt, const float* __restrict__ Alr,
        const float* __restrict__ Aim, const float* __restrict__ Cr,
        const float* __restrict__ Ci, float* __restrict__ Kt) {
    int tid = blockIdx.x * 256 + threadIdx.x;
    int d = tid & (D_ - 1);
    int j = tid >> 10;
    float dt = expf(log_dt[d]);
    float acc = 0.f;
    #pragma unroll
    for (int n = 0; n < 4; ++n) {
        float ar = -expf(Alr[d * 4 + n]);
        float ai = Aim[d * 4 + n];
        float wr = ar * dt, wi = ai * dt;
        float ew = expf(wr);
        float sw, cw; sincosf(wi, &sw, &cw);
        float ur = ew * cw - 1.0f, ui = ew * sw;
        float inv = 1.0f / (ar * ar + ai * ai);
        float bdr = (ur * ar + ui * ai) * inv;
        float bdi = (ui * ar - ur * ai) * inv;
        float cr = Cr[d * 4 + n], ci = Ci[d * 4 + n];
        float cbr = cr * bdr - ci * bdi;
        float cbi = cr * bdi + ci * bdr;
        float ej = expf(wr * (float)j);
        float sj, cj; sincosf(wi * (float)j, &sj, &cj);
        acc += 2.0f * ej * (cbr * cj - cbi * sj);
    }
    Kt[j * D_ + d] = acc;
}

// ---------------- transpose+cast: src f32 [R][C] -> dst bf16 [C][R], batched z
__global__ __launch_bounds__(256) void k_tcast(
        const float* __restrict__ src0, u16* __restrict__ dst0, int R, int C) {
    __shared__ float tile[64][65];
    const float* src = src0 + (size_t)blockIdx.z * R * C;
    u16* dst = dst0 + (size_t)blockIdx.z * R * C;
    int c0 = blockIdx.x * 64;
    int r0 = blockIdx.y * 64;
    int t = threadIdx.x;
    #pragma unroll
    for (int p = 0; p < 4; ++p) {
        int fid = p * 256 + t;
        int rr = fid >> 4, cc = (fid & 15) * 4;
        float4 v = *(const float4*)&src[(size_t)(r0 + rr) * C + c0 + cc];
        tile[rr][cc + 0] = v.x; tile[rr][cc + 1] = v.y;
        tile[rr][cc + 2] = v.z; tile[rr][cc + 3] = v.w;
    }
    __syncthreads();
    #pragma unroll
    for (int p = 0; p < 4; ++p) {
        int fid = p * 256 + t;
        int rr = fid >> 4, cc = (fid & 15) * 4;
        ushort4 o;
        o.x = f2bf(tile[cc + 0][rr]);
        o.y = f2bf(tile[cc + 1][rr]);
        o.z = f2bf(tile[cc + 2][rr]);
        o.w = f2bf(tile[cc + 3][rr]);
        *(ushort4*)&dst[(size_t)(c0 + rr) * R + r0 + cc] = o;
    }
}

// ---------------- K1: encoder MFMA: hb[m][e] = xb[m][:]·WeT[e][:] + be[e] ---
// M=32768, N=1024, K=128 (single shot). 128x128 tile, 2048 blocks.
__global__ __launch_bounds__(256) void k_enc_mfma(
        const u16* __restrict__ xb, const u16* __restrict__ WeT,
        const float* __restrict__ be, u16* __restrict__ hb) {
    __shared__ u16 As[128 * 128];   // 32 KB, swizzled granules
    __shared__ u16 Bs[128 * 128];   // 32 KB
    int t = threadIdx.x;
    int lane = t & 63, wid = t >> 6;
    int wr = wid & 1, wc = wid >> 1;
    int orig = blockIdx.x;
    int wgid = (orig & 7) * 256 + (orig >> 3);   // 2048 % 8 == 0
    int m0 = (wgid >> 3) * 128;
    int e0 = (wgid & 7) * 128;

    // stage: 32 chunks per matrix (chunk = 64 lanes x 16B), 8 per wave
    #pragma unroll
    for (int c = 0; c < 8; ++c) {
        int ch = wid * 8 + c;
        int r = ch * 4 + (lane >> 4);             // row 0..127
        int g = (lane & 15) ^ (r & 15);           // swizzled source granule
        gld16(&xb[(size_t)(m0 + r) * 128 + g * 8], &As[ch * 512]);
        gld16(&WeT[(size_t)(e0 + r) * 128 + g * 8], &Bs[ch * 512]);
    }
    int co4[4];
    #pragma unroll
    for (int kh = 0; kh < 4; ++kh)
        co4[kh] = ((((lane >> 4) + kh * 4) ^ (lane & 15)) * 8);
    int arow[4], brow[4];
    #pragma unroll
    for (int i = 0; i < 4; ++i) arow[i] = (wr * 64 + i * 16 + (lane & 15)) * 128;
    #pragma unroll
    for (int q = 0; q < 4; ++q) brow[q] = (wc * 64 + q * 16 + (lane & 15)) * 128;

    __syncthreads();
    f32x4 acc[4][4] = {};
    #pragma unroll
    for (int kh = 0; kh < 4; ++kh) {
        bf16x8 af[4], bfr[4];
        #pragma unroll
        for (int i = 0; i < 4; ++i) af[i] = *(const bf16x8*)&As[arow[i] + co4[kh]];
        #pragma unroll
        for (int q = 0; q < 4; ++q) bfr[q] = *(const bf16x8*)&Bs[brow[q] + co4[kh]];
        __builtin_amdgcn_s_setprio(1);
        #pragma unroll
        for (int i = 0; i < 4; ++i)
            #pragma unroll
            for (int q = 0; q < 4; ++q)
                acc[i][q] = __builtin_amdgcn_mfma_f32_16x16x32_bf16(af[i], bfr[q], acc[i][q], 0, 0, 0);
        __builtin_amdgcn_s_setprio(0);
    }
    #pragma unroll
    for (int q = 0; q < 4; ++q) {
        int e = e0 + wc * 64 + q * 16 + (lane & 15);
        float bias = be[e];
        #pragma unroll
        for (int i = 0; i < 4; ++i) {
            #pragma unroll
            for (int r = 0; r < 4; ++r) {
                int m = m0 + wr * 64 + i * 16 + (lane >> 4) * 4 + r;
                hb[(size_t)m * 1024 + e] = f2bf(acc[i][q][r] + bias);
            }
        }
    }
}

// ---------------- K2: causal 64-tap conv + D*skip + GELU -------------------
__global__ __launch_bounds__(256) void k_conv(
        const u16* __restrict__ hb, const float* __restrict__ Kt,
        const float* __restrict__ Dv, u16* __restrict__ yg) {
    __shared__ float hs[128][64];
    int b = blockIdx.z;
    int l0 = blockIdx.y * 64;
    int d0 = blockIdx.x * 64;
    int t = threadIdx.x;
    int dl = t & 63, lg = t >> 6;
    #pragma unroll
    for (int p = 0; p < 8; ++p) {
        int fid = p * 256 + t;
        int r = fid >> 4, c4 = fid & 15;
        int l = l0 - 64 + r;
        float4 v = make_float4(0.f, 0.f, 0.f, 0.f);
        if (l >= 0) {
            ushort4 u = *(const ushort4*)&hb[((size_t)b * 1024 + l) * 1024 + d0 + c4 * 4];
            v = make_float4(bf2f(u.x), bf2f(u.y), bf2f(u.z), bf2f(u.w));
        }
        *(float4*)&hs[r][c4 * 4] = v;
    }
    float kr[64];
    #pragma unroll
    for (int j = 0; j < 64; ++j) kr[j] = Kt[j * 1024 + d0 + dl];
    float Dd = Dv[d0 + dl];
    __syncthreads();
    float acc[16] = {};
    int rbase = lg * 16 + 1;
    #pragma unroll
    for (int s = 0; s < 15; ++s) {
        float hv = hs[rbase + s][dl];
        #pragma unroll
        for (int i = 0; i <= 14; ++i)
            if (i <= s) acc[i] = fmaf(kr[i + 63 - s], hv, acc[i]);
    }
    #pragma unroll
    for (int s = 15; s < 64; ++s) {
        float hv = hs[rbase + s][dl];
        #pragma unroll
        for (int i = 0; i < 16; ++i)
            acc[i] = fmaf(kr[i + 63 - s], hv, acc[i]);
    }
    #pragma unroll
    for (int s = 64; s < 79; ++s) {
        float hv = hs[rbase + s][dl];
        #pragma unroll
        for (int i = 1; i < 16; ++i)
            if (i >= s - 63) acc[i] = fmaf(kr[i + 63 - s], hv, acc[i]);
    }
    #pragma unroll
    for (int i = 0; i < 16; ++i) {
        int l = l0 + lg * 16 + i;
        float z = hs[64 + lg * 16 + i][dl];
        float y = acc[i] + Dd * z;
        yg[((size_t)b * 1024 + l) * 1024 + d0 + dl] = f2bf(gelu_tanh(y));
    }
}

// ---------------- K3: GLU GEMM (bf16 MFMA, dbuf + swizzle) -----------------
// 128(m) x 64 pairs; BK=64, 16 k-steps. Granule swizzle: g_lds = g ^ (row&7).
__global__ __launch_bounds__(256) void k_glu_mfma(
        const u16* __restrict__ yg, const u16* __restrict__ WgT,
        const float* __restrict__ bg, u16* __restrict__ hb) {
    __shared__ u16 As[2][8192];   // 2 x 16 KB
    __shared__ u16 Bs[2][8192];
    int t = threadIdx.x;
    int lane = t & 63, wid = t >> 6;
    int wr = wid & 1, wc = wid >> 1;

    int orig = blockIdx.x;
    int wgid = (orig & 7) * 512 + (orig >> 3);   // XCD swizzle (4096 % 8 == 0)
    int m0 = (wgid >> 4) * 128;
    int p0 = (wgid & 15) * 64;

    int gsrc = (((lane & 7) ^ (lane >> 3)) * 8);  // swizzled source k-offset
    int rA[4], nB[4];
    #pragma unroll
    for (int c = 0; c < 4; ++c) {
        int r = (wid * 4 + c) * 8 + (lane >> 3);
        rA[c] = m0 + r;
        int pairIdx = ((r >> 5) << 4) | (r & 15);
        int half = (r >> 4) & 1;
        nB[c] = half * 1024 + p0 + pairIdx;
    }
    int co[2];
    co[0] = (((lane >> 4) + 0) ^ (lane & 7)) * 8;
    co[1] = (((lane >> 4) + 4) ^ (lane & 7)) * 8;
    int arow[4], brow[4];
    #pragma unroll
    for (int i = 0; i < 4; ++i) arow[i] = (wr * 64 + i * 16 + (lane & 15)) * 64;
    #pragma unroll
    for (int q = 0; q < 4; ++q) brow[q] = (wc * 64 + q * 16 + (lane & 15)) * 64;

    f32x4 acc[4][4] = {};
    // prologue: stage kt=0 into buf 0
    #pragma unroll
    for (int c = 0; c < 4; ++c) {
        int ch = wid * 4 + c;
        gld16(&yg[(size_t)rA[c] * 1024 + gsrc], &As[0][ch * 512]);
        gld16(&WgT[(size_t)nB[c] * 1024 + gsrc], &Bs[0][ch * 512]);
    }
    __syncthreads();
    int cur = 0;
    for (int kt = 0; kt < 16; ++kt) {
        if (kt < 15) {
            int k0 = (kt + 1) * 64;
            #pragma unroll
            for (int c = 0; c < 4; ++c) {
                int ch = wid * 4 + c;
                gld16(&yg[(size_t)rA[c] * 1024 + k0 + gsrc], &As[cur ^ 1][ch * 512]);
                gld16(&WgT[(size_t)nB[c] * 1024 + k0 + gsrc], &Bs[cur ^ 1][ch * 512]);
            }
        }
        #pragma unroll
        for (int kh = 0; kh < 2; ++kh) {
            bf16x8 af[4], bfr[4];
            #pragma unroll
            for (int i = 0; i < 4; ++i) af[i] = *(const bf16x8*)&As[cur][arow[i] + co[kh]];
            #pragma unroll
            for (int q = 0; q < 4; ++q) bfr[q] = *(const bf16x8*)&Bs[cur][brow[q] + co[kh]];
            __builtin_amdgcn_s_setprio(1);
            #pragma unroll
            for (int i = 0; i < 4; ++i)
                #pragma unroll
                for (int q = 0; q < 4; ++q)
                    acc[i][q] = __builtin_amdgcn_mfma_f32_16x16x32_bf16(af[i], bfr[q], acc[i][q], 0, 0, 0);
            __builtin_amdgcn_s_setprio(0);
        }
        __syncthreads();
        cur ^= 1;
    }
    // epilogue: pairs (frag 2qq=g1, 2qq+1=g2), residual in-place
    #pragma unroll
    for (int i = 0; i < 4; ++i) {
        #pragma unroll
        for (int qq = 0; qq < 2; ++qq) {
            int pair = (wc * 2 + qq) * 16 + (lane & 15);
            int col = p0 + pair;
            float b1v = bg[col];
            float b2v = bg[1024 + col];
            #pragma unroll
            for (int r = 0; r < 4; ++r) {
                int m = m0 + wr * 64 + i * 16 + (lane >> 4) * 4 + r;
                float g1 = acc[i][qq * 2][r] + b1v;
                float g2 = acc[i][qq * 2 + 1][r] + b2v;
                size_t idx = (size_t)m * 1024 + col;
                float hf = bf2f(hb[idx]);
                hb[idx] = f2bf(hf + g1 * sigmoidf(g2));
            }
        }
    }
}

// ---------------- K4: LayerNorm in-place on hb ------------------------------
__global__ __launch_bounds__(256) void k_ln(
        u16* __restrict__ hb, const float* __restrict__ gamma,
        const float* __restrict__ beta) {
    int row = blockIdx.x;
    int t = threadIdx.x;
    size_t base = (size_t)row * 1024;
    ushort4 u = *(const ushort4*)&hb[base + t * 4];
    float v0 = bf2f(u.x), v1 = bf2f(u.y), v2 = bf2f(u.z), v3 = bf2f(u.w);
    float s = v0 + v1 + v2 + v3;
    float s2 = v0 * v0 + v1 * v1 + v2 * v2 + v3 * v3;
    #pragma unroll
    for (int off = 32; off > 0; off >>= 1) {
        s += __shfl_down(s, off);
        s2 += __shfl_down(s2, off);
    }
    __shared__ float rs[4], rs2[4];
    int wid = t >> 6, lane = t & 63;
    if (lane == 0) { rs[wid] = s; rs2[wid] = s2; }
    __syncthreads();
    float ts = rs[0] + rs[1] + rs[2] + rs[3];
    float ts2 = rs2[0] + rs2[1] + rs2[2] + rs2[3];
    float mean = ts * (1.0f / 1024.0f);
    float var = ts2 * (1.0f / 1024.0f) - mean * mean;
    float rstd = rsqrtf(var + 1e-5f);
    float4 gm = *(const float4*)&gamma[t * 4];
    float4 bt = *(const float4*)&beta[t * 4];
    ushort4 o;
    o.x = f2bf((v0 - mean) * rstd * gm.x + bt.x);
    o.y = f2bf((v1 - mean) * rstd * gm.y + bt.y);
    o.z = f2bf((v2 - mean) * rstd * gm.z + bt.z);
    o.w = f2bf((v3 - mean) * rstd * gm.w + bt.w);
    *(ushort4*)&hb[base + t * 4] = o;
}

// ---------------- K5: decoder GEMM (dbuf + swizzle) + transpose store ------
__global__ __launch_bounds__(256) void k_dec_mfma(
        const u16* __restrict__ hb, const u16* __restrict__ WdT,
        const float* __restrict__ bd, float* __restrict__ out) {
    __shared__ __align__(16) char smem[65536];
    u16* As = (u16*)smem;               // 2 x 16 KB
    u16* Bs = (u16*)(smem + 32768);     // 2 x 16 KB
    float* Ts = (float*)smem;           // 64*132*4 = 33792 B (reused)
    int t = threadIdx.x;
    int lane = t & 63, wid = t >> 6;
    int wr = wid & 1, wc = wid >> 1;
    int m0 = blockIdx.x * 128;
    int bb = m0 >> 10, l0 = m0 & 1023;

    int gsrc = (((lane & 7) ^ (lane >> 3)) * 8);
    int rr4[4];
    #pragma unroll
    for (int c = 0; c < 4; ++c) rr4[c] = (wid * 4 + c) * 8 + (lane >> 3);
    int co[2];
    co[0] = (((lane >> 4) + 0) ^ (lane & 7)) * 8;
    co[1] = (((lane >> 4) + 4) ^ (lane & 7)) * 8;
    int arow[4], brow[4];
    #pragma unroll
    for (int i = 0; i < 4; ++i) arow[i] = (wr * 64 + i * 16 + (lane & 15)) * 64;
    #pragma unroll
    for (int q = 0; q < 4; ++q) brow[q] = (wc * 64 + q * 16 + (lane & 15)) * 64;

    f32x4 acc[4][4] = {};
    #pragma unroll
    for (int c = 0; c < 4; ++c) {
        int ch = wid * 4 + c;
        gld16(&hb[(size_t)(m0 + rr4[c]) * 1024 + gsrc], &As[0 * 8192 + ch * 512]);
        gld16(&WdT[(size_t)rr4[c] * 1024 + gsrc], &Bs[0 * 8192 + ch * 512]);
    }
    __syncthreads();
    int cur = 0;
    for (int kt = 0; kt < 16; ++kt) {
        if (kt < 15) {
            int k0 = (kt + 1) * 64;
            #pragma unroll
            for (int c = 0; c < 4; ++c) {
                int ch = wid * 4 + c;
                gld16(&hb[(size_t)(m0 + rr4[c]) * 1024 + k0 + gsrc], &As[(cur ^ 1) * 8192 + ch * 512]);
                gld16(&WdT[(size_t)rr4[c] * 1024 + k0 + gsrc], &Bs[(cur ^ 1) * 8192 + ch * 512]);
            }
        }
        #pragma unroll
        for (int kh = 0; kh < 2; ++kh) {
            bf16x8 af[4], bfr[4];
            #pragma unroll
            for (int i = 0; i < 4; ++i) af[i] = *(const bf16x8*)&As[cur * 8192 + arow[i] + co[kh]];
            #pragma unroll
            for (int q = 0; q < 4; ++q) bfr[q] = *(const bf16x8*)&Bs[cur * 8192 + brow[q] + co[kh]];
            __builtin_amdgcn_s_setprio(1);
            #pragma unroll
            for (int i = 0; i < 4; ++i)
                #pragma unroll
                for (int q = 0; q < 4; ++q)
                    acc[i][q] = __builtin_amdgcn_mfma_f32_16x16x32_bf16(af[i], bfr[q], acc[i][q], 0, 0, 0);
            __builtin_amdgcn_s_setprio(0);
        }
        __syncthreads();
        cur ^= 1;
    }
    __syncthreads();
    #pragma unroll
    for (int ro = 0; ro < 2; ++ro) {
        if (wc == ro) {
            #pragma unroll
            for (int i = 0; i < 4; ++i)
                #pragma unroll
                for (int q = 0; q < 4; ++q) {
                    int sl = q * 16 + (lane & 15);
                    float bias = bd[ro * 64 + sl];
                    #pragma unroll
                    for (int r = 0; r < 4; ++r) {
                        int ml = wr * 64 + i * 16 + (lane >> 4) * 4 + r;
                        Ts[sl * 132 + ml] = acc[i][q][r] + bias;
                    }
                }
        }
        __syncthreads();
        #pragma unroll
        for (int p = 0; p < 8; ++p) {
            int fid = p * 256 + t;
            int sl = fid >> 5, c = (fid & 31) * 4;
            float4 v = *(const float4*)&Ts[sl * 132 + c];
            *(float4*)&out[(size_t)bb * 131072 + (size_t)(ro * 64 + sl) * 1024 + l0 + c] = v;
        }
        __syncthreads();
    }
}

extern "C" void kernel_launch(void* const* d_in, const int* in_sizes, int n_in,
                              void* d_out, int out_size, void* d_ws, size_t ws_size,
                              hipStream_t stream) {
    (void)in_sizes; (void)n_in; (void)out_size; (void)ws_size;
    const float* x   = (const float*)d_in[0];
    const float* We  = (const float*)d_in[1];
    const float* be  = (const float*)d_in[2];
    const float* ldt = (const float*)d_in[3];
    const float* Alr = (const float*)d_in[4];
    const float* Aim = (const float*)d_in[5];
    const float* Cr  = (const float*)d_in[6];
    const float* Ci  = (const float*)d_in[7];
    const float* Dv  = (const float*)d_in[8];
    const float* Wg  = (const float*)d_in[9];
    const float* bg  = (const float*)d_in[10];
    const float* gam = (const float*)d_in[11];
    const float* bet = (const float*)d_in[12];
    const float* Wd  = (const float*)d_in[13];
    const float* bd  = (const float*)d_in[14];
    float* out = (float*)d_out;

    u16* hb = (u16*)d_ws;                       // 67 MB
    u16* yg = hb + 33554432ull;                 // 67 MB
    float* Kt = (float*)(yg + 33554432ull);     // 256 KB
    u16* WgT = (u16*)(Kt + 65536);              // 4 MB
    u16* WdT = WgT + 2097152ull;                // 256 KB
    u16* WeT = WdT + 131072ull;                 // 256 KB
    u16* xb  = yg;                              // alias: xb dead before conv writes yg

    k_tcast<<<dim3(32, 16, 1), 256, 0, stream>>>(Wg, WgT, 1024, 2048);
    k_tcast<<<dim3(2, 16, 1), 256, 0, stream>>>(Wd, WdT, 1024, 128);
    k_tcast<<<dim3(16, 2, 1), 256, 0, stream>>>(We, WeT, 128, 1024);
    k_tcast<<<dim3(16, 2, 32), 256, 0, stream>>>(x, xb, 128, 1024);
    k_ssmk<<<256, 256, 0, stream>>>(ldt, Alr, Aim, Cr, Ci, Kt);
    k_enc_mfma<<<2048, 256, 0, stream>>>(xb, WeT, be, hb);
    k_conv<<<dim3(16, 16, 32), 256, 0, stream>>>(hb, Kt, Dv, yg);
    k_glu_mfma<<<4096, 256, 0, stream>>>(yg, WgT, bg, hb);
    k_ln<<<32768, 256, 0, stream>>>(hb, gam, bet);
    k_dec_mfma<<<256, 256, 0, stream>>>(hb, WdT, bd, out);
}

// Round 5
// 343.804 us; speedup vs baseline: 5.5702x; 1.0629x over previous
//
#include <hip/hip_runtime.h>
#include <hip/hip_bf16.h>
#include <math.h>

#define B_ 32
#define S_ 128
#define L_ 1024
#define D_ 1024

typedef unsigned short u16;
typedef __attribute__((ext_vector_type(8))) __bf16 bf16x8;
typedef __attribute__((ext_vector_type(4))) float f32x4;

__device__ __forceinline__ float bf2f(u16 u) {
    return __uint_as_float(((unsigned)u) << 16);
}
__device__ __forceinline__ u16 f2bf(float f) {
    unsigned u = __float_as_uint(f);
    u += 0x7FFF + ((u >> 16) & 1);
    return (u16)(u >> 16);
}
__device__ __forceinline__ float gelu_tanh(float x) {
    float x3 = x * x * x;
    float t = tanhf(0.7978845608028654f * (x + 0.044715f * x3));
    return 0.5f * x * (1.0f + t);
}
__device__ __forceinline__ float sigmoidf(float x) {
    return 1.0f / (1.0f + expf(-x));
}
__device__ __forceinline__ void gld16(const void* g, void* l) {
    __builtin_amdgcn_global_load_lds((const __attribute__((address_space(1))) void*)g,
                                     (__attribute__((address_space(3))) void*)l, 16, 0, 0);
}

// ---------------- K0: S4D SSM kernel, writes Kt[j][d] (j-major, 64x1024) ----
__global__ __launch_bounds__(256) void k_ssmk(
        const float* __restrict__ log_dt, const float* __restrict__ Alr,
        const float* __restrict__ Aim, const float* __restrict__ Cr,
        const float* __restrict__ Ci, float* __restrict__ Kt) {
    int tid = blockIdx.x * 256 + threadIdx.x;
    int d = tid & (D_ - 1);
    int j = tid >> 10;
    float dt = expf(log_dt[d]);
    float acc = 0.f;
    #pragma unroll
    for (int n = 0; n < 4; ++n) {
        float ar = -expf(Alr[d * 4 + n]);
        float ai = Aim[d * 4 + n];
        float wr = ar * dt, wi = ai * dt;
        float ew = expf(wr);
        float sw, cw; sincosf(wi, &sw, &cw);
        float ur = ew * cw - 1.0f, ui = ew * sw;
        float inv = 1.0f / (ar * ar + ai * ai);
        float bdr = (ur * ar + ui * ai) * inv;
        float bdi = (ui * ar - ur * ai) * inv;
        float cr = Cr[d * 4 + n], ci = Ci[d * 4 + n];
        float cbr = cr * bdr - ci * bdi;
        float cbi = cr * bdi + ci * bdr;
        float ej = expf(wr * (float)j);
        float sj, cj; sincosf(wi * (float)j, &sj, &cj);
        acc += 2.0f * ej * (cbr * cj - cbi * sj);
    }
    Kt[j * D_ + d] = acc;
}

// ---------------- transpose+cast: src f32 [R][C] -> dst bf16 [C][R], batched z
__global__ __launch_bounds__(256) void k_tcast(
        const float* __restrict__ src0, u16* __restrict__ dst0, int R, int C) {
    __shared__ float tile[64][65];
    const float* src = src0 + (size_t)blockIdx.z * R * C;
    u16* dst = dst0 + (size_t)blockIdx.z * R * C;
    int c0 = blockIdx.x * 64;
    int r0 = blockIdx.y * 64;
    int t = threadIdx.x;
    #pragma unroll
    for (int p = 0; p < 4; ++p) {
        int fid = p * 256 + t;
        int rr = fid >> 4, cc = (fid & 15) * 4;
        float4 v = *(const float4*)&src[(size_t)(r0 + rr) * C + c0 + cc];
        tile[rr][cc + 0] = v.x; tile[rr][cc + 1] = v.y;
        tile[rr][cc + 2] = v.z; tile[rr][cc + 3] = v.w;
    }
    __syncthreads();
    #pragma unroll
    for (int p = 0; p < 4; ++p) {
        int fid = p * 256 + t;
        int rr = fid >> 4, cc = (fid & 15) * 4;
        ushort4 o;
        o.x = f2bf(tile[cc + 0][rr]);
        o.y = f2bf(tile[cc + 1][rr]);
        o.z = f2bf(tile[cc + 2][rr]);
        o.w = f2bf(tile[cc + 3][rr]);
        *(ushort4*)&dst[(size_t)(c0 + rr) * R + r0 + cc] = o;
    }
}

// ---------------- K1: encoder MFMA: hb[m][e] = xb[m][:]·WeT[e][:] + be[e] ---
__global__ __launch_bounds__(256) void k_enc_mfma(
        const u16* __restrict__ xb, const u16* __restrict__ WeT,
        const float* __restrict__ be, u16* __restrict__ hb) {
    __shared__ u16 As[128 * 128];
    __shared__ u16 Bs[128 * 128];
    int t = threadIdx.x;
    int lane = t & 63, wid = t >> 6;
    int wr = wid & 1, wc = wid >> 1;
    int orig = blockIdx.x;
    int wgid = (orig & 7) * 256 + (orig >> 3);
    int m0 = (wgid >> 3) * 128;
    int e0 = (wgid & 7) * 128;

    #pragma unroll
    for (int c = 0; c < 8; ++c) {
        int ch = wid * 8 + c;
        int r = ch * 4 + (lane >> 4);
        int g = (lane & 15) ^ (r & 15);
        gld16(&xb[(size_t)(m0 + r) * 128 + g * 8], &As[ch * 512]);
        gld16(&WeT[(size_t)(e0 + r) * 128 + g * 8], &Bs[ch * 512]);
    }
    int co4[4];
    #pragma unroll
    for (int kh = 0; kh < 4; ++kh)
        co4[kh] = ((((lane >> 4) + kh * 4) ^ (lane & 15)) * 8);
    int arow[4], brow[4];
    #pragma unroll
    for (int i = 0; i < 4; ++i) arow[i] = (wr * 64 + i * 16 + (lane & 15)) * 128;
    #pragma unroll
    for (int q = 0; q < 4; ++q) brow[q] = (wc * 64 + q * 16 + (lane & 15)) * 128;

    __syncthreads();
    f32x4 acc[4][4] = {};
    #pragma unroll
    for (int kh = 0; kh < 4; ++kh) {
        bf16x8 af[4], bfr[4];
        #pragma unroll
        for (int i = 0; i < 4; ++i) af[i] = *(const bf16x8*)&As[arow[i] + co4[kh]];
        #pragma unroll
        for (int q = 0; q < 4; ++q) bfr[q] = *(const bf16x8*)&Bs[brow[q] + co4[kh]];
        __builtin_amdgcn_s_setprio(1);
        #pragma unroll
        for (int i = 0; i < 4; ++i)
            #pragma unroll
            for (int q = 0; q < 4; ++q)
                acc[i][q] = __builtin_amdgcn_mfma_f32_16x16x32_bf16(af[i], bfr[q], acc[i][q], 0, 0, 0);
        __builtin_amdgcn_s_setprio(0);
    }
    #pragma unroll
    for (int q = 0; q < 4; ++q) {
        int e = e0 + wc * 64 + q * 16 + (lane & 15);
        float bias = be[e];
        #pragma unroll
        for (int i = 0; i < 4; ++i) {
            #pragma unroll
            for (int r = 0; r < 4; ++r) {
                int m = m0 + wr * 64 + i * 16 + (lane >> 4) * 4 + r;
                hb[(size_t)m * 1024 + e] = f2bf(acc[i][q][r] + bias);
            }
        }
    }
}

// ---------------- K2: causal 64-tap conv + D*skip + GELU -------------------
__global__ __launch_bounds__(256) void k_conv(
        const u16* __restrict__ hb, const float* __restrict__ Kt,
        const float* __restrict__ Dv, u16* __restrict__ yg) {
    __shared__ float hs[128][64];
    int b = blockIdx.z;
    int l0 = blockIdx.y * 64;
    int d0 = blockIdx.x * 64;
    int t = threadIdx.x;
    int dl = t & 63, lg = t >> 6;
    #pragma unroll
    for (int p = 0; p < 8; ++p) {
        int fid = p * 256 + t;
        int r = fid >> 4, c4 = fid & 15;
        int l = l0 - 64 + r;
        float4 v = make_float4(0.f, 0.f, 0.f, 0.f);
        if (l >= 0) {
            ushort4 u = *(const ushort4*)&hb[((size_t)b * 1024 + l) * 1024 + d0 + c4 * 4];
            v = make_float4(bf2f(u.x), bf2f(u.y), bf2f(u.z), bf2f(u.w));
        }
        *(float4*)&hs[r][c4 * 4] = v;
    }
    float kr[64];
    #pragma unroll
    for (int j = 0; j < 64; ++j) kr[j] = Kt[j * 1024 + d0 + dl];
    float Dd = Dv[d0 + dl];
    __syncthreads();
    float acc[16] = {};
    int rbase = lg * 16 + 1;
    #pragma unroll
    for (int s = 0; s < 15; ++s) {
        float hv = hs[rbase + s][dl];
        #pragma unroll
        for (int i = 0; i <= 14; ++i)
            if (i <= s) acc[i] = fmaf(kr[i + 63 - s], hv, acc[i]);
    }
    #pragma unroll
    for (int s = 15; s < 64; ++s) {
        float hv = hs[rbase + s][dl];
        #pragma unroll
        for (int i = 0; i < 16; ++i)
            acc[i] = fmaf(kr[i + 63 - s], hv, acc[i]);
    }
    #pragma unroll
    for (int s = 64; s < 79; ++s) {
        float hv = hs[rbase + s][dl];
        #pragma unroll
        for (int i = 1; i < 16; ++i)
            if (i >= s - 63) acc[i] = fmaf(kr[i + 63 - s], hv, acc[i]);
    }
    #pragma unroll
    for (int i = 0; i < 16; ++i) {
        int l = l0 + lg * 16 + i;
        float z = hs[64 + lg * 16 + i][dl];
        float y = acc[i] + Dd * z;
        yg[((size_t)b * 1024 + l) * 1024 + d0 + dl] = f2bf(gelu_tanh(y));
    }
}

// ---------------- K3: GLU GEMM 256x256 8-phase (bf16 MFMA) -----------------
// M=32768, N=2048 (128 pairs/tile), K=1024, BK=64, 8 waves, 128 KiB LDS.
// Stage units per K-tile: U0=A rows{0-63,128-191}, U2=B rows{q01 of each wave},
// U3=B rows{q23}, U1=A rows{64-127,192-255}. Counted vmcnt: 2 @ phi0, 4 @ phi2.
__global__ __launch_bounds__(512, 2) void k_glu256(
        const u16* __restrict__ yg, const u16* __restrict__ WgT,
        const float* __restrict__ bg, u16* __restrict__ hb) {
    __shared__ u16 Asm[2][16384];   // 2 x 32 KB  [256 rows][64 k]
    __shared__ u16 Bsm[2][16384];   // 2 x 32 KB
    int t = threadIdx.x;
    int lane = t & 63, wid = t >> 6;
    int wr = wid >> 2, wc = wid & 3;

    int orig = blockIdx.x;
    int wgid = (orig & 7) * 128 + (orig >> 3);   // 1024 % 8 == 0, bijective
    int m0 = (wgid >> 3) * 256;
    int p0g = (wgid & 7) * 128;

    // staging geometry: chunk = 8 rows x 64k, 2 chunks/wave/unit
    int rl = lane >> 3;
    int gsw = ((lane & 7) ^ rl) * 8;           // swizzled source k-elem offset
    int ch0 = wid * 2, ch1 = wid * 2 + 1;
    // A unit U0 rows (U1 = +64)
    int rA0 = (ch0 >> 3) * 128 + (ch0 & 7) * 8 + rl;
    int rA1 = (ch1 >> 3) * 128 + (ch1 & 7) * 8 + rl;
    int dA0 = ((ch0 >> 3) * 128 + (ch0 & 7) * 8) * 64;
    int dA1 = ((ch1 >> 3) * 128 + (ch1 & 7) * 8) * 64;
    // B unit U2 tile rows (U3 = +32)
    int rB0 = (ch0 >> 2) * 64 + (ch0 & 3) * 8 + rl;
    int rB1 = (ch1 >> 2) * 64 + (ch1 & 3) * 8 + rl;
    int dB0 = ((ch0 >> 2) * 64 + (ch0 & 3) * 8) * 64;
    int dB1 = ((ch1 >> 2) * 64 + (ch1 & 3) * 8) * 64;
    // B tile row -> WgT row (pairing); U3 row = U2 row + 16 in WgT space
    int gB0 = ((rB0 >> 4) & 1) * 1024 + p0g + (((rB0 >> 5) << 4) | (rB0 & 15));
    int gB1 = ((rB1 >> 4) & 1) * 1024 + p0g + (((rB1 >> 5) << 4) | (rB1 & 15));

    // fragment read bases
    int co0 = (((lane >> 4) + 0) ^ (lane & 7)) * 8;
    int co1 = (((lane >> 4) + 4) ^ (lane & 7)) * 8;
    int abase = (wr * 128 + (lane & 15)) * 64;
    int bbase = (wc * 64 + (lane & 15)) * 64;

#define STG_A0(BUF, K0) { gld16(&yg[(size_t)(m0 + rA0) * 1024 + (K0) + gsw], &Asm[BUF][dA0]); \
                          gld16(&yg[(size_t)(m0 + rA1) * 1024 + (K0) + gsw], &Asm[BUF][dA1]); }
#define STG_A1(BUF, K0) { gld16(&yg[(size_t)(m0 + rA0 + 64) * 1024 + (K0) + gsw], &Asm[BUF][dA0 + 4096]); \
                          gld16(&yg[(size_t)(m0 + rA1 + 64) * 1024 + (K0) + gsw], &Asm[BUF][dA1 + 4096]); }
#define STG_B0(BUF, K0) { gld16(&WgT[(size_t)gB0 * 1024 + (K0) + gsw], &Bsm[BUF][dB0]); \
                          gld16(&WgT[(size_t)gB1 * 1024 + (K0) + gsw], &Bsm[BUF][dB1]); }
#define STG_B1(BUF, K0) { gld16(&WgT[(size_t)(gB0 + 16) * 1024 + (K0) + gsw], &Bsm[BUF][dB0 + 2048]); \
                          gld16(&WgT[(size_t)(gB1 + 16) * 1024 + (K0) + gsw], &Bsm[BUF][dB1 + 2048]); }
#define RD_A(MH) { _Pragma("unroll") for (int i = 0; i < 4; ++i) { \
        a0[i][0] = *(const bf16x8*)&Ac[abase + (MH) * 4096 + i * 1024 + co0]; \
        a0[i][1] = *(const bf16x8*)&Ac[abase + (MH) * 4096 + i * 1024 + co1]; } }
#define RD_B(BB, OFS) { _Pragma("unroll") for (int q = 0; q < 2; ++q) { \
        BB[q][0] = *(const bf16x8*)&Bc[bbase + (OFS) + q * 1024 + co0]; \
        BB[q][1] = *(const bf16x8*)&Bc[bbase + (OFS) + q * 1024 + co1]; } }
#define MFMA_CL(MI, BB, NQ) { __builtin_amdgcn_s_setprio(1); \
    _Pragma("unroll") for (int i = 0; i < 4; ++i) \
        _Pragma("unroll") for (int q = 0; q < 2; ++q) { \
            acc[(MI) * 4 + i][(NQ) + q] = __builtin_amdgcn_mfma_f32_16x16x32_bf16(a0[i][0], BB[q][0], acc[(MI) * 4 + i][(NQ) + q], 0, 0, 0); \
            acc[(MI) * 4 + i][(NQ) + q] = __builtin_amdgcn_mfma_f32_16x16x32_bf16(a0[i][1], BB[q][1], acc[(MI) * 4 + i][(NQ) + q], 0, 0, 0); } \
    __builtin_amdgcn_s_setprio(0); }

    f32x4 acc[8][4] = {};
    bf16x8 a0[4][2], b0[2][2], b1[2][2];

    // prologue: stage tile 0 in unit order U0, U2, U3, U1
    STG_A0(0, 0); STG_B0(0, 0); STG_B1(0, 0); STG_A1(0, 0);

    int cur = 0;
    for (int kt = 0; kt < 15; ++kt) {
        const u16* Ac = &Asm[cur][0];
        const u16* Bc = &Bsm[cur][0];
        int nxt = cur ^ 1, k1 = (kt + 1) * 64;
        // phi0: needs U0,U2 (+U3 certified); allow 1 unit (U1) outstanding
        asm volatile("s_waitcnt vmcnt(2)" ::: "memory");
        __builtin_amdgcn_s_barrier();
        RD_A(0); RD_B(b0, 0);
        STG_A0(nxt, k1);
        __builtin_amdgcn_s_barrier();
        MFMA_CL(0, b0, 0);
        // phi1: b23 (certified at phi0)
        RD_B(b1, 2048);
        STG_B0(nxt, k1);
        __builtin_amdgcn_s_barrier();
        MFMA_CL(0, b1, 2);
        // phi2: needs U1; allow 2 units (U0',U2') outstanding
        asm volatile("s_waitcnt vmcnt(4)" ::: "memory");
        __builtin_amdgcn_s_barrier();
        RD_A(1);
        STG_B1(nxt, k1);
        __builtin_amdgcn_s_barrier();
        MFMA_CL(1, b0, 0);
        // phi3
        STG_A1(nxt, k1);
        __builtin_amdgcn_s_barrier();
        MFMA_CL(1, b1, 2);
        cur = nxt;
    }
    // peel kt = 15 (no staging)
    {
        const u16* Ac = &Asm[cur][0];
        const u16* Bc = &Bsm[cur][0];
        asm volatile("s_waitcnt vmcnt(2)" ::: "memory");
        __builtin_amdgcn_s_barrier();
        RD_A(0); RD_B(b0, 0);
        MFMA_CL(0, b0, 0);
        RD_B(b1, 2048);
        MFMA_CL(0, b1, 2);
        asm volatile("s_waitcnt vmcnt(0)" ::: "memory");
        __builtin_amdgcn_s_barrier();
        RD_A(1);
        MFMA_CL(1, b0, 0);
        MFMA_CL(1, b1, 2);
    }
    // epilogue: GLU activation + residual in-place
    #pragma unroll
    for (int i = 0; i < 8; ++i) {
        #pragma unroll
        for (int tt = 0; tt < 2; ++tt) {
            int col = p0g + (wc * 2 + tt) * 16 + (lane & 15);
            float b1v = bg[col];
            float b2v = bg[1024 + col];
            #pragma unroll
            for (int r = 0; r < 4; ++r) {
                int m = m0 + wr * 128 + i * 16 + (lane >> 4) * 4 + r;
                size_t idx = (size_t)m * 1024 + col;
                float g1 = acc[i][tt * 2][r] + b1v;
                float g2 = acc[i][tt * 2 + 1][r] + b2v;
                hb[idx] = f2bf(bf2f(hb[idx]) + g1 * sigmoidf(g2));
            }
        }
    }
#undef STG_A0
#undef STG_A1
#undef STG_B0
#undef STG_B1
#undef RD_A
#undef RD_B
#undef MFMA_CL
}

// ---------------- K4: LayerNorm in-place on hb ------------------------------
__global__ __launch_bounds__(256) void k_ln(
        u16* __restrict__ hb, const float* __restrict__ gamma,
        const float* __restrict__ beta) {
    int row = blockIdx.x;
    int t = threadIdx.x;
    size_t base = (size_t)row * 1024;
    ushort4 u = *(const ushort4*)&hb[base + t * 4];
    float v0 = bf2f(u.x), v1 = bf2f(u.y), v2 = bf2f(u.z), v3 = bf2f(u.w);
    float s = v0 + v1 + v2 + v3;
    float s2 = v0 * v0 + v1 * v1 + v2 * v2 + v3 * v3;
    #pragma unroll
    for (int off = 32; off > 0; off >>= 1) {
        s += __shfl_down(s, off);
        s2 += __shfl_down(s2, off);
    }
    __shared__ float rs[4], rs2[4];
    int wid = t >> 6, lane = t & 63;
    if (lane == 0) { rs[wid] = s; rs2[wid] = s2; }
    __syncthreads();
    float ts = rs[0] + rs[1] + rs[2] + rs[3];
    float ts2 = rs2[0] + rs2[1] + rs2[2] + rs2[3];
    float mean = ts * (1.0f / 1024.0f);
    float var = ts2 * (1.0f / 1024.0f) - mean * mean;
    float rstd = rsqrtf(var + 1e-5f);
    float4 gm = *(const float4*)&gamma[t * 4];
    float4 bt = *(const float4*)&beta[t * 4];
    ushort4 o;
    o.x = f2bf((v0 - mean) * rstd * gm.x + bt.x);
    o.y = f2bf((v1 - mean) * rstd * gm.y + bt.y);
    o.z = f2bf((v2 - mean) * rstd * gm.z + bt.z);
    o.w = f2bf((v3 - mean) * rstd * gm.w + bt.w);
    *(ushort4*)&hb[base + t * 4] = o;
}

// ---------------- K5: decoder GEMM (dbuf + swizzle) + transpose store ------
__global__ __launch_bounds__(256) void k_dec_mfma(
        const u16* __restrict__ hb, const u16* __restrict__ WdT,
        const float* __restrict__ bd, float* __restrict__ out) {
    __shared__ __align__(16) char smem[65536];
    u16* As = (u16*)smem;
    u16* Bs = (u16*)(smem + 32768);
    float* Ts = (float*)smem;
    int t = threadIdx.x;
    int lane = t & 63, wid = t >> 6;
    int wr = wid & 1, wc = wid >> 1;
    int m0 = blockIdx.x * 128;
    int bb = m0 >> 10, l0 = m0 & 1023;

    int gsrc = (((lane & 7) ^ (lane >> 3)) * 8);
    int rr4[4];
    #pragma unroll
    for (int c = 0; c < 4; ++c) rr4[c] = (wid * 4 + c) * 8 + (lane >> 3);
    int co[2];
    co[0] = (((lane >> 4) + 0) ^ (lane & 7)) * 8;
    co[1] = (((lane >> 4) + 4) ^ (lane & 7)) * 8;
    int arow[4], brow[4];
    #pragma unroll
    for (int i = 0; i < 4; ++i) arow[i] = (wr * 64 + i * 16 + (lane & 15)) * 64;
    #pragma unroll
    for (int q = 0; q < 4; ++q) brow[q] = (wc * 64 + q * 16 + (lane & 15)) * 64;

    f32x4 acc[4][4] = {};
    #pragma unroll
    for (int c = 0; c < 4; ++c) {
        int ch = wid * 4 + c;
        gld16(&hb[(size_t)(m0 + rr4[c]) * 1024 + gsrc], &As[0 * 8192 + ch * 512]);
        gld16(&WdT[(size_t)rr4[c] * 1024 + gsrc], &Bs[0 * 8192 + ch * 512]);
    }
    __syncthreads();
    int cur = 0;
    for (int kt = 0; kt < 16; ++kt) {
        if (kt < 15) {
            int k0 = (kt + 1) * 64;
            #pragma unroll
            for (int c = 0; c < 4; ++c) {
                int ch = wid * 4 + c;
                gld16(&hb[(size_t)(m0 + rr4[c]) * 1024 + k0 + gsrc], &As[(cur ^ 1) * 8192 + ch * 512]);
                gld16(&WdT[(size_t)rr4[c] * 1024 + k0 + gsrc], &Bs[(cur ^ 1) * 8192 + ch * 512]);
            }
        }
        #pragma unroll
        for (int kh = 0; kh < 2; ++kh) {
            bf16x8 af[4], bfr[4];
            #pragma unroll
            for (int i = 0; i < 4; ++i) af[i] = *(const bf16x8*)&As[cur * 8192 + arow[i] + co[kh]];
            #pragma unroll
            for (int q = 0; q < 4; ++q) bfr[q] = *(const bf16x8*)&Bs[cur * 8192 + brow[q] + co[kh]];
            __builtin_amdgcn_s_setprio(1);
            #pragma unroll
            for (int i = 0; i < 4; ++i)
                #pragma unroll
                for (int q = 0; q < 4; ++q)
                    acc[i][q] = __builtin_amdgcn_mfma_f32_16x16x32_bf16(af[i], bfr[q], acc[i][q], 0, 0, 0);
            __builtin_amdgcn_s_setprio(0);
        }
        __syncthreads();
        cur ^= 1;
    }
    __syncthreads();
    #pragma unroll
    for (int ro = 0; ro < 2; ++ro) {
        if (wc == ro) {
            #pragma unroll
            for (int i = 0; i < 4; ++i)
                #pragma unroll
                for (int q = 0; q < 4; ++q) {
                    int sl = q * 16 + (lane & 15);
                    float bias = bd[ro * 64 + sl];
                    #pragma unroll
                    for (int r = 0; r < 4; ++r) {
                        int ml = wr * 64 + i * 16 + (lane >> 4) * 4 + r;
                        Ts[sl * 132 + ml] = acc[i][q][r] + bias;
                    }
                }
        }
        __syncthreads();
        #pragma unroll
        for (int p = 0; p < 8; ++p) {
            int fid = p * 256 + t;
            int sl = fid >> 5, c = (fid & 31) * 4;
            float4 v = *(const float4*)&Ts[sl * 132 + c];
            *(float4*)&out[(size_t)bb * 131072 + (size_t)(ro * 64 + sl) * 1024 + l0 + c] = v;
        }
        __syncthreads();
    }
}

extern "C" void kernel_launch(void* const* d_in, const int* in_sizes, int n_in,
                              void* d_out, int out_size, void* d_ws, size_t ws_size,
                              hipStream_t stream) {
    (void)in_sizes; (void)n_in; (void)out_size; (void)ws_size;
    const float* x   = (const float*)d_in[0];
    const float* We  = (const float*)d_in[1];
    const float* be  = (const float*)d_in[2];
    const float* ldt = (const float*)d_in[3];
    const float* Alr = (const float*)d_in[4];
    const float* Aim = (const float*)d_in[5];
    const float* Cr  = (const float*)d_in[6];
    const float* Ci  = (const float*)d_in[7];
    const float* Dv  = (const float*)d_in[8];
    const float* Wg  = (const float*)d_in[9];
    const float* bg  = (const float*)d_in[10];
    const float* gam = (const float*)d_in[11];
    const float* bet = (const float*)d_in[12];
    const float* Wd  = (const float*)d_in[13];
    const float* bd  = (const float*)d_in[14];
    float* out = (float*)d_out;

    u16* hb = (u16*)d_ws;                       // 67 MB
    u16* yg = hb + 33554432ull;                 // 67 MB
    float* Kt = (float*)(yg + 33554432ull);     // 256 KB
    u16* WgT = (u16*)(Kt + 65536);              // 4 MB
    u16* WdT = WgT + 2097152ull;                // 256 KB
    u16* WeT = WdT + 131072ull;                 // 256 KB
    u16* xb  = yg;                              // alias: xb dead before conv writes yg

    k_tcast<<<dim3(32, 16, 1), 256, 0, stream>>>(Wg, WgT, 1024, 2048);
    k_tcast<<<dim3(2, 16, 1), 256, 0, stream>>>(Wd, WdT, 1024, 128);
    k_tcast<<<dim3(16, 2, 1), 256, 0, stream>>>(We, WeT, 128, 1024);
    k_tcast<<<dim3(16, 2, 32), 256, 0, stream>>>(x, xb, 128, 1024);
    k_ssmk<<<256, 256, 0, stream>>>(ldt, Alr, Aim, Cr, Ci, Kt);
    k_enc_mfma<<<2048, 256, 0, stream>>>(xb, WeT, be, hb);
    k_conv<<<dim3(16, 16, 32), 256, 0, stream>>>(hb, Kt, Dv, yg);
    k_glu256<<<1024, 512, 0, stream>>>(yg, WgT, bg, hb);
    k_ln<<<32768, 256, 0, stream>>>(hb, gam, bet);
    k_dec_mfma<<<256, 256, 0, stream>>>(hb, WdT, bd, out);
}